// Round 15
// baseline (343.091 us; speedup 1.0000x reference)
//
#include <hip/hip_runtime.h>

constexpr int DIN = 128, HIDF = 8;
constexpr int LOGD = 8, DPB = 1 << LOGD;    // dsts per bucket (256)
constexpr int BE = 8192;                     // edges per partition block
constexpr int NBCAP = 512;                   // max buckets (N <= 128K); PB1 row stride
constexpr int SCAP = 16384;                  // sort LDS capacity

// ---- bf16 pack/unpack helpers (RNE) ----
__device__ inline unsigned bfpack(float lo, float hi) {
  unsigned a = __float_as_uint(lo), b = __float_as_uint(hi);
  unsigned ra = (a + 0x7fffu + ((a >> 16) & 1u)) >> 16;
  unsigned rb = (b + 0x7fffu + ((b >> 16) & 1u)) >> 16;
  return ra | (rb << 16);
}
__device__ inline float bflo(unsigned u) { return __uint_as_float(u << 16); }
__device__ inline float bfhi(unsigned u) { return __uint_as_float(u & 0xffff0000u); }

// ---------------- layer-1 projection: xp[N,8] = x[N,128] @ w[128,8] + b ----------------
__global__ __launch_bounds__(256) void k_proj1(
    const float* __restrict__ x, const float* __restrict__ w,
    const float* __restrict__ b, float* __restrict__ xp, int N)
{
  __shared__ float ws_[DIN * HIDF];
  __shared__ float xs[32 * 132];
  int t = threadIdx.x;
  ((float4*)ws_)[t] = ((const float4*)w)[t];
  int base = blockIdx.x * 32;
#pragma unroll
  for (int i = 0; i < 4; i++) {
    int f4 = t + i * 256;
    int nl = f4 >> 5;
    if (base + nl < N) {
      float4 v = ((const float4*)(x + (size_t)base * DIN))[f4];
      int col = (f4 & 31) << 2;
      *((float4*)&xs[nl * 132 + col]) = v;
    }
  }
  __syncthreads();
  int nl = t >> 3, j = t & 7;
  int n0 = base + nl;
  if (n0 >= N) return;
  float acc = b[j];
  const float* xr = &xs[nl * 132];
#pragma unroll 8
  for (int k = 0; k < DIN; k++) acc = fmaf(xr[k], ws_[k * HIDF + j], acc);
  xp[(size_t)n0 * HIDF + j] = acc;
}

// -- layer-1 pack: per-type 32B records {bf16 xp[8] (16B), f32 a0,a1 (8B), pad} + dst alphas --
__global__ __launch_bounds__(256) void k_pack1(
    const float* __restrict__ xp, int N,
    const float* __restrict__ ps0, float* __restrict__ rec0,
    const float* __restrict__ ps1, float* __restrict__ rec1,
    const float* __restrict__ pd0, float* __restrict__ od0,
    const float* __restrict__ pd1, float* __restrict__ od1)
{
  int n = blockIdx.x * blockDim.x + threadIdx.x;
  if (n >= N) return;
  float4 a4 = ((const float4*)xp)[(size_t)n * 2];
  float4 b4 = ((const float4*)xp)[(size_t)n * 2 + 1];
  float xv[8] = {a4.x, a4.y, a4.z, a4.w, b4.x, b4.y, b4.z, b4.w};
  uint4 pk;
  pk.x = bfpack(xv[0], xv[1]); pk.y = bfpack(xv[2], xv[3]);
  pk.z = bfpack(xv[4], xv[5]); pk.w = bfpack(xv[6], xv[7]);
#define DOT2(p, s0, s1)                                               \
  float s0 = 0.f, s1 = 0.f;                                           \
  for (int d = 0; d < 4; d++) { s0 += xv[d] * p[d]; s1 += xv[4 + d] * p[4 + d]; }
  if (rec0) {
    DOT2(ps0, s0, s1)
    ((uint4*)rec0)[(size_t)n * 2] = pk;
    ((float4*)rec0)[(size_t)n * 2 + 1] = make_float4(s0, s1, 0.f, 0.f);
  }
  if (rec1) {
    DOT2(ps1, s0, s1)
    ((uint4*)rec1)[(size_t)n * 2] = pk;
    ((float4*)rec1)[(size_t)n * 2 + 1] = make_float4(s0, s1, 0.f, 0.f);
  }
  if (pd0) { DOT2(pd0, s0, s1) ((float2*)od0)[n] = make_float2(s0, s1); }
  if (pd1) { DOT2(pd1, s0, s1) ((float2*)od1)[n] = make_float2(s0, s1); }
#undef DOT2
}

// ---------------- partition pass 1: per-(block,bucket) coarse histogram ----------------
__global__ __launch_bounds__(512) void k_bcount(
    const int* __restrict__ d0, const int* __restrict__ d1, const int* __restrict__ d2,
    int E, int nblocks, int* __restrict__ PB1)
{
  int ty = blockIdx.y;
  const int* dst = ty == 0 ? d0 : (ty == 1 ? d1 : d2);
  __shared__ int hist[NBCAP];
  int t = threadIdx.x;
  hist[t] = 0;
  __syncthreads();
  int blk = blockIdx.x;
  int e0 = blk * BE, e1 = min(E, e0 + BE);
  int qbase = e0 >> 2, nq = (e1 - e0) >> 2;
#pragma unroll
  for (int i = 0; i < 4; i++) {
    int q = i * 512 + t;
    if (q < nq) {
      int4 v = ((const int4*)dst)[qbase + q];
      atomicAdd(&hist[v.x >> LOGD], 1);
      atomicAdd(&hist[v.y >> LOGD], 1);
      atomicAdd(&hist[v.z >> LOGD], 1);
      atomicAdd(&hist[v.w >> LOGD], 1);
    }
  }
  __syncthreads();
  PB1[((size_t)(ty * NBCAP) + t) * nblocks + blk] = hist[t];
}

// ---------------- partition pass 2: scan per-bucket block counts (in place) ----------------
__global__ __launch_bounds__(512) void k_bscan(
    int* __restrict__ PB1, int* __restrict__ TOTS,
    int nblocks, int NBmax, int nb0, int nb1, int nb2)
{
  int ty = blockIdx.y;
  int NBt = ty == 0 ? nb0 : (ty == 1 ? nb1 : nb2);
  int bk = blockIdx.x;
  if (bk >= NBt) return;
  int* p = PB1 + ((size_t)(ty * NBCAP) + bk) * nblocks;
  int t = threadIdx.x;
  int v = (t < nblocks) ? p[t] : 0;
  int lane = t & 63, wv = t >> 6;
  int x = v;
#pragma unroll
  for (int o = 1; o < 64; o <<= 1) { int u = __shfl_up(x, o, 64); if (lane >= o) x += u; }
  __shared__ int ws[8];
  if (lane == 63) ws[wv] = x;
  __syncthreads();
  if (t == 0) { int s = 0; for (int k = 0; k < 8; k++) { int tmp = ws[k]; ws[k] = s; s += tmp; } }
  __syncthreads();
  int excl = x - v + ws[wv];
  if (t < nblocks) p[t] = excl;
  if (t == nblocks - 1) TOTS[ty * NBmax + bk] = excl + v;
}

// ---------------- partition pass 3: bucket start offsets (per type, within PART+ty*E) -------
__global__ __launch_bounds__(512) void k_bstart(
    const int* __restrict__ TOTS, int* __restrict__ BSTART,
    int NBmax, int nb0, int nb1, int nb2)
{
  int ty = blockIdx.x;
  int NBt = ty == 0 ? nb0 : (ty == 1 ? nb1 : nb2);
  int t = threadIdx.x;
  int v = (t < NBt) ? TOTS[ty * NBmax + t] : 0;
  int lane = t & 63, wv = t >> 6;
  int x = v;
#pragma unroll
  for (int o = 1; o < 64; o <<= 1) { int u = __shfl_up(x, o, 64); if (lane >= o) x += u; }
  __shared__ int ws[8];
  if (lane == 63) ws[wv] = x;
  __syncthreads();
  if (t == 0) { int s = 0; for (int k = 0; k < 8; k++) { int tmp = ws[k]; ws[k] = s; s += tmp; } }
  __syncthreads();
  int excl = x - v + ws[wv];
  int* bs = BSTART + (size_t)ty * (NBmax + 1);
  if (t < NBt) bs[t] = excl;
  if (t == NBt - 1) bs[NBt] = excl + v;
}

// ---- partition pass 4: LDS-staged bucket-partition (bkt-table write-out, no bin search) ----
__global__ __launch_bounds__(512) void k_bplace(
    const int* __restrict__ e0p, const int* __restrict__ e1p, const int* __restrict__ e2p,
    int E, int nblocks, int NBmax, int nb0, int nb1, int nb2,
    const int* __restrict__ PB1, const int* __restrict__ BSTART,
    int* __restrict__ PART)
{
  int ty = blockIdx.y;
  const int* src = ty == 0 ? e0p : (ty == 1 ? e1p : e2p);
  const int* dst = src + E;
  int NBt = ty == 0 ? nb0 : (ty == 1 ? nb1 : nb2);
  int* part = PART + (size_t)ty * E;
  __shared__ int hist[NBCAP];
  __shared__ int lscan[NBCAP + 1];
  __shared__ int base[NBCAP];   // bst + bpref - lscan, fused
  __shared__ int stage[BE];
  __shared__ short bkt[BE];
  __shared__ int ws[8];
  int t = threadIdx.x;
  hist[t] = 0;
  __syncthreads();
  int blk = blockIdx.x;
  int e0 = blk * BE, e1 = min(E, e0 + BE);
  int cnt = e1 - e0;
  int qbase = e0 >> 2, nq = cnt >> 2;
  int dreg[16], sreg[16];
  unsigned short lr[16];
#pragma unroll
  for (int i = 0; i < 4; i++) {
    int q = i * 512 + t;
    if (q < nq) {
      int4 dq = ((const int4*)dst)[qbase + q];
      int4 sq = ((const int4*)src)[qbase + q];
      dreg[i * 4 + 0] = dq.x; dreg[i * 4 + 1] = dq.y;
      dreg[i * 4 + 2] = dq.z; dreg[i * 4 + 3] = dq.w;
      sreg[i * 4 + 0] = sq.x; sreg[i * 4 + 1] = sq.y;
      sreg[i * 4 + 2] = sq.z; sreg[i * 4 + 3] = sq.w;
#pragma unroll
      for (int k = 0; k < 4; k++)
        lr[i * 4 + k] = (unsigned short)atomicAdd(&hist[dreg[i * 4 + k] >> LOGD], 1);
    } else {
#pragma unroll
      for (int k = 0; k < 4; k++) dreg[i * 4 + k] = -1;
    }
  }
  __syncthreads();
  // exclusive scan of 512 hist bins
  {
    int v = hist[t];
    int lane = t & 63, wv = t >> 6;
    int x = v;
#pragma unroll
    for (int o = 1; o < 64; o <<= 1) { int u = __shfl_up(x, o, 64); if (lane >= o) x += u; }
    if (lane == 63) ws[wv] = x;
    __syncthreads();
    if (t == 0) { int s = 0; for (int k = 0; k < 8; k++) { int tmp = ws[k]; ws[k] = s; s += tmp; } }
    __syncthreads();
    int excl = x - v + ws[wv];
    lscan[t] = excl;
    if (t == NBCAP - 1) lscan[NBCAP] = excl + v;
  }
  if (t < NBt)
    base[t] = BSTART[(size_t)ty * (NBmax + 1) + t]
            + PB1[((size_t)(ty * NBCAP) + t) * nblocks + blk];
  __syncthreads();
  // fill bkt table: each thread handles its bucket's range
  {
    int b = t;
    if (b < NBt) {
      int j0 = lscan[b], j1 = lscan[b + 1];
      base[b] -= j0;                       // fuse: part index = base[b] + j
      for (int j = j0; j < j1; j++) bkt[j] = (short)b;
    }
  }
  // stage edges sorted by bucket
#pragma unroll
  for (int i = 0; i < 16; i++) {
    int d = dreg[i];
    if (d >= 0) {
      int bk2 = d >> LOGD;
      stage[lscan[bk2] + lr[i]] = (sreg[i] << LOGD) | (d & (DPB - 1));
    }
  }
  __syncthreads();
  for (int j = t; j < cnt; j += 512)
    part[base[bkt[j]] + j] = stage[j];
}

// ---- partition pass 5: per-bucket counting sort (single PART read, rank-capture) ----
__global__ __launch_bounds__(512) void k_sort(
    int* __restrict__ PART, const int* __restrict__ BSTART, int NBmax, int E,
    int nb0, int nb1, int nb2, int n0, int n1, int n2,
    int nmx1, int* __restrict__ OFFs)
{
  int ty = blockIdx.y;
  int NBt = ty == 0 ? nb0 : (ty == 1 ? nb1 : nb2);
  int Nt  = ty == 0 ? n0 : (ty == 1 ? n1 : n2);
  int bk = blockIdx.x;
  if (bk >= NBt) return;
  int* part = PART + (size_t)ty * E;
  const int* bs = BSTART + (size_t)ty * (NBmax + 1);
  int s0 = bs[bk], s1 = bs[bk + 1];
  int cnt = s1 - s0;
  __shared__ int hist[DPB];
  __shared__ int binoff[DPB];
  __shared__ int sorted[SCAP];
  __shared__ int ws[4];
  int t = threadIdx.x;
  if (t < DPB) hist[t] = 0;
  __syncthreads();
  int myv[32];
  unsigned short myr[32];
#pragma unroll
  for (int it = 0; it < 32; it++) {
    int j = s0 + it * 512 + t;
    if (j < s1) {
      int v = part[j];
      myv[it] = v;
      myr[it] = (unsigned short)atomicAdd(&hist[v & (DPB - 1)], 1);
    } else myv[it] = -1;
  }
  __syncthreads();
  {
    int v = (t < DPB) ? hist[t] : 0;
    int lane = t & 63, wv = t >> 6;
    int x = v;
#pragma unroll
    for (int o = 1; o < 64; o <<= 1) { int u = __shfl_up(x, o, 64); if (lane >= o) x += u; }
    if (t < DPB && lane == 63) ws[wv] = x;
    __syncthreads();
    if (t == 0) { int s = 0; for (int k = 0; k < 4; k++) { int tmp = ws[k]; ws[k] = s; s += tmp; } }
    __syncthreads();
    if (t < DPB) binoff[t] = x - v + ws[wv];
  }
  __syncthreads();
  int d0 = bk << LOGD;
  if (t < DPB && d0 + t < Nt) OFFs[(size_t)ty * nmx1 + d0 + t] = s0 + binoff[t];
  if (bk == NBt - 1 && t == 0) OFFs[(size_t)ty * nmx1 + Nt] = s1;
#pragma unroll
  for (int it = 0; it < 32; it++) {
    int v = myv[it];
    if (v >= 0) sorted[binoff[v & (DPB - 1)] + myr[it]] = v >> LOGD;
  }
  __syncthreads();
  for (int j = t; j < cnt; j += 512) part[s0 + j] = sorted[j];
}

// -- layer-1 gather: CSR, 32 lanes/dst, bf16 records, type->XCD swizzle, reg accumulate --
__global__ __launch_bounds__(512) void k_gather1(
    const int* __restrict__ PART, const int* __restrict__ OFFs, int nmx1, int E, int gG,
    const float* __restrict__ r0, const float* __restrict__ ad0, float* __restrict__ o0, int n0,
    const float* __restrict__ r1, const float* __restrict__ ad1, float* __restrict__ o1, int n1,
    const float* __restrict__ r2, const float* __restrict__ ad2, float* __restrict__ o2, int n2)
{
  int bid = blockIdx.x;
  int rr = bid & 7, m = bid >> 3;
  int ty, xb;
  if (rr < 3)      { ty = 0; xb = m * 3 + rr; }
  else if (rr < 6) { ty = 1; xb = m * 3 + (rr - 3); }
  else             { ty = 2; xb = m * 2 + (rr - 6); }
  if (xb >= gG) return;
  const float* rec = ty == 0 ? r0 : (ty == 1 ? r1 : r2);
  const float* ad_ = ty == 0 ? ad0 : (ty == 1 ? ad1 : ad2);
  float* out = ty == 0 ? o0 : (ty == 1 ? o1 : o2);
  int Nt = ty == 0 ? n0 : (ty == 1 ? n1 : n2);
  int g = xb * 512 + threadIdx.x;
  int d = g >> 5, l = g & 31;                // 32 lanes per dst
  if (d >= Nt) return;
  const int* off = OFFs + (size_t)ty * nmx1;
  const int* part = PART + (size_t)ty * E;
  int i0 = off[d], i1 = off[d + 1];
  float2 adv = ((const float2*)ad_)[d];
  float s0 = 0.f, s1 = 0.f;
  float acc[8] = {0.f, 0.f, 0.f, 0.f, 0.f, 0.f, 0.f, 0.f};
  for (int i = i0 + l; i < i1; i += 32) {
    int s = part[i];
    uint4 q = ((const uint4*)rec)[(size_t)s * 2];
    float4 ax = ((const float4*)rec)[(size_t)s * 2 + 1];
    float a0 = ax.x + adv.x; a0 = a0 > 0.f ? a0 : 0.2f * a0;
    float a1 = ax.y + adv.y; a1 = a1 > 0.f ? a1 : 0.2f * a1;
    float e0 = __expf(a0), e1 = __expf(a1);
    s0 += e0; s1 += e1;
    acc[0] += e0 * bflo(q.x); acc[1] += e0 * bfhi(q.x);
    acc[2] += e0 * bflo(q.y); acc[3] += e0 * bfhi(q.y);
    acc[4] += e1 * bflo(q.z); acc[5] += e1 * bfhi(q.z);
    acc[6] += e1 * bflo(q.w); acc[7] += e1 * bfhi(q.w);
  }
#pragma unroll
  for (int mm = 1; mm < 32; mm <<= 1) {
    s0 += __shfl_xor(s0, mm, 32);
    s1 += __shfl_xor(s1, mm, 32);
#pragma unroll
    for (int k = 0; k < 8; k++) acc[k] += __shfl_xor(acc[k], mm, 32);
  }
  if (l) return;
  float r0i = 1.f / (s0 + 1e-16f), r1i = 1.f / (s1 + 1e-16f);
  float4 q0 = make_float4(fmaxf(acc[0] * r0i, 0.f), fmaxf(acc[1] * r0i, 0.f),
                          fmaxf(acc[2] * r0i, 0.f), fmaxf(acc[3] * r0i, 0.f));
  float4 q1 = make_float4(fmaxf(acc[4] * r1i, 0.f), fmaxf(acc[5] * r1i, 0.f),
                          fmaxf(acc[6] * r1i, 0.f), fmaxf(acc[7] * r1i, 0.f));
  ((float4*)out)[(size_t)d * 2] = q0;
  ((float4*)out)[(size_t)d * 2 + 1] = q1;
}

// ------- layer-2 gather: CSR, 16 lanes/dst, 16B bf16 records, reg accumulate -------
__global__ __launch_bounds__(512) void k_gather2(
    const int* __restrict__ PART, const int* __restrict__ OFFs, int nmx1, int E,
    int ti0, int ti1,
    const float* __restrict__ r0, const float* __restrict__ ad0, float* __restrict__ o0,
    const float* __restrict__ r1, const float* __restrict__ ad1, float* __restrict__ o1, int N)
{
  int zz = blockIdx.y;
  int ty = zz == 0 ? ti0 : ti1;
  const float* rec = zz == 0 ? r0 : r1;
  const float* ad_ = zz == 0 ? ad0 : ad1;
  float* out = zz == 0 ? o0 : o1;
  int g = blockIdx.x * 512 + threadIdx.x;
  int d = g >> 4, l = g & 15;
  if (d >= N) return;
  const int* off = OFFs + (size_t)ty * nmx1;
  const int* part = PART + (size_t)ty * E;
  int i0 = off[d], i1 = off[d + 1];
  float adv = ad_[d];
  float ssum = 0.f;
  float acc[7] = {0.f, 0.f, 0.f, 0.f, 0.f, 0.f, 0.f};
  for (int i = i0 + l; i < i1; i += 16) {
    int s = part[i];
    uint4 q = ((const uint4*)rec)[s];
    float a = bfhi(q.w) + adv; a = a > 0.f ? a : 0.2f * a;
    float ex = __expf(a);
    ssum += ex;
    acc[0] += ex * bflo(q.x); acc[1] += ex * bfhi(q.x);
    acc[2] += ex * bflo(q.y); acc[3] += ex * bfhi(q.y);
    acc[4] += ex * bflo(q.z); acc[5] += ex * bfhi(q.z);
    acc[6] += ex * bflo(q.w);
  }
#pragma unroll
  for (int mm = 1; mm < 16; mm <<= 1) {
    ssum += __shfl_xor(ssum, mm, 16);
#pragma unroll
    for (int k = 0; k < 7; k++) acc[k] += __shfl_xor(acc[k], mm, 16);
  }
  if (l) return;
  float r = 1.f / (ssum + 1e-16f);
  float4 q0 = make_float4(fmaxf(acc[0] * r, 0.f), fmaxf(acc[1] * r, 0.f),
                          fmaxf(acc[2] * r, 0.f), fmaxf(acc[3] * r, 0.f));
  float4 q1 = make_float4(fmaxf(acc[4] * r, 0.f), fmaxf(acc[5] * r, 0.f),
                          fmaxf(acc[6] * r, 0.f), 0.f);
  ((float4*)out)[(size_t)d * 2] = q0;
  ((float4*)out)[(size_t)d * 2 + 1] = q1;
}

// ---------------- semantic-attention reduction (batched over 2 inputs) ----------------
__global__ __launch_bounds__(256) void k_red(
    const float* __restrict__ hA, const float* __restrict__ hB, int N, int F,
    const float* __restrict__ kw, const float* __restrict__ kb,
    float* __restrict__ redA, float* __restrict__ redB)
{
  const float* h = blockIdx.y ? hB : hA;
  float* red = blockIdx.y ? redB : redA;
  __shared__ float kws[64], kbs[8];
  __shared__ float sm[256 * 8];
  int t = threadIdx.x;
  if (t < F * F) kws[t] = kw[t];
  if (t < F) kbs[t] = kb[t];
  __syncthreads();
  float acc[8] = {0, 0, 0, 0, 0, 0, 0, 0};
  for (int n = blockIdx.x * 256 + t; n < N; n += gridDim.x * 256) {
    const float* row = h + (size_t)n * 8;
    float xv[8];
    for (int k = 0; k < F; k++) xv[k] = row[k];
    for (int f = 0; f < F; f++) {
      float s = kbs[f];
      for (int k = 0; k < F; k++) s += xv[k] * kws[k * F + f];
      acc[f] += tanhf(s);
    }
  }
  for (int f = 0; f < 8; f++) sm[t * 8 + f] = (f < F) ? acc[f] : 0.f;
  __syncthreads();
  for (int s2 = 128; s2 > 0; s2 >>= 1) {
    if (t < s2)
      for (int f = 0; f < 8; f++) sm[t * 8 + f] += sm[(t + s2) * 8 + f];
    __syncthreads();
  }
  if (t < F) atomicAdd(&red[t], sm[t]);
}

// ---------------- semantic attention weights (tiny) ----------------
__global__ void k_attn(const float* __restrict__ red, const float* __restrict__ q,
                       int T, int F, float invN, float* __restrict__ attn)
{
  if (threadIdx.x != 0 || blockIdx.x != 0) return;
  float v[4]; float m = -1e30f;
  for (int t2 = 0; t2 < T; t2++) {
    float s = 0.f;
    for (int f = 0; f < F; f++) s += q[f] * red[t2 * F + f];
    s *= invN;
    v[t2] = s; m = fmaxf(m, s);
  }
  float sum = 0.f;
  for (int t2 = 0; t2 < T; t2++) { v[t2] = __expf(v[t2] - m); sum += v[t2]; }
  for (int t2 = 0; t2 < T; t2++) attn[t2] = v[t2] / sum;
}

// -- layer-2 projection: fused semantic combine (+relu) + packed 16B bf16 record + dst alphas --
__global__ __launch_bounds__(256) void k_proj2(
    const float* __restrict__ h0, const float* __restrict__ h1,
    const float* __restrict__ attn, int N,
    const float* __restrict__ w, const float* __restrict__ b,
    float* __restrict__ rec2, const float* __restrict__ psrc,
    const float* __restrict__ pd0, float* __restrict__ od0,
    const float* __restrict__ pd1, float* __restrict__ od1)
{
  int n = blockIdx.x * blockDim.x + threadIdx.x;
  if (n >= N) return;
  float a0 = 1.f, a1 = 0.f;
  if (attn) { a0 = attn[0]; a1 = attn[1]; }
  float4 u0 = ((const float4*)h0)[(size_t)n * 2];
  float4 u1 = ((const float4*)h0)[(size_t)n * 2 + 1];
  float xv[8] = {u0.x, u0.y, u0.z, u0.w, u1.x, u1.y, u1.z, u1.w};
  if (h1) {
    float4 v0 = ((const float4*)h1)[(size_t)n * 2];
    float4 v1 = ((const float4*)h1)[(size_t)n * 2 + 1];
    float yv[8] = {v0.x, v0.y, v0.z, v0.w, v1.x, v1.y, v1.z, v1.w};
    for (int j = 0; j < 8; j++) xv[j] = a0 * xv[j] + a1 * yv[j];
  }
  for (int j = 0; j < 8; j++) xv[j] = fmaxf(xv[j], 0.f);
  float y[7];
  for (int j = 0; j < 7; j++) y[j] = b[j];
  for (int k = 0; k < 8; k++) {
    float xk = xv[k];
    for (int j = 0; j < 7; j++) y[j] += xk * w[k * 7 + j];
  }
  float ssrc = 0.f;
  for (int j = 0; j < 7; j++) ssrc += y[j] * psrc[j];
  uint4 pk;
  pk.x = bfpack(y[0], y[1]); pk.y = bfpack(y[2], y[3]);
  pk.z = bfpack(y[4], y[5]); pk.w = bfpack(y[6], ssrc);
  ((uint4*)rec2)[n] = pk;
#define DOD(p, o)                                       \
  if (p) {                                              \
    float s = 0.f;                                      \
    for (int j = 0; j < 7; j++) s += y[j] * p[j];       \
    o[n] = s;                                           \
  }
  DOD(pd0, od0) DOD(pd1, od1)
#undef DOD
}

// ---------------- final combine + log_softmax ----------------
__global__ __launch_bounds__(256) void k_final(
    const float* __restrict__ h0, const float* __restrict__ h1,
    const float* __restrict__ attn, float* __restrict__ out, int N)
{
  int n = blockIdx.x * blockDim.x + threadIdx.x;
  if (n >= N) return;
  float a0 = attn[0], a1 = attn[1];
  const float* r0 = h0 + (size_t)n * 8;
  const float* r1 = h1 + (size_t)n * 8;
  float v[7]; float m = -1e30f;
  for (int c = 0; c < 7; c++) { float t = a0 * r0[c] + a1 * r1[c]; v[c] = t; m = fmaxf(m, t); }
  float sum = 0.f;
  for (int c = 0; c < 7; c++) sum += __expf(v[c] - m);
  float lse = m + logf(sum);
  for (int c = 0; c < 7; c++) out[(size_t)n * 7 + c] = v[c] - lse;
}

extern "C" void kernel_launch(void* const* d_in, const int* in_sizes, int n_in,
                              void* d_out, int out_size, void* d_ws, size_t ws_size,
                              hipStream_t stream)
{
  const float* x_p  = (const float*)d_in[0];
  const float* x_a  = (const float*)d_in[1];
  const int*   eipp = (const int*)d_in[2];
  const int*   eipa = (const int*)d_in[3];
  const int*   eiap = (const int*)d_in[4];
  const float* w1p  = (const float*)d_in[5];
  const float* b1p  = (const float*)d_in[6];
  const float* w1a  = (const float*)d_in[7];
  const float* b1a  = (const float*)d_in[8];
  const float* as1pp = (const float*)d_in[9];
  const float* ad1pp = (const float*)d_in[10];
  const float* as1pa = (const float*)d_in[11];
  const float* ad1pa = (const float*)d_in[12];
  const float* as1ap = (const float*)d_in[13];
  const float* ad1ap = (const float*)d_in[14];
  const float* kw1 = (const float*)d_in[15];
  const float* kb1 = (const float*)d_in[16];
  const float* q1  = (const float*)d_in[17];
  const float* w2p = (const float*)d_in[18];
  const float* b2p = (const float*)d_in[19];
  const float* w2a = (const float*)d_in[20];
  const float* b2a = (const float*)d_in[21];
  const float* as2pp = (const float*)d_in[22];
  const float* ad2pp = (const float*)d_in[23];
  // d_in[24]=as2pa, d_in[25]=ad2pa unused: pa edges only feed author nodes,
  // and author layer-2 output is dead (final output is papers only).
  const float* as2ap = (const float*)d_in[26];
  const float* ad2ap = (const float*)d_in[27];
  const float* kw2 = (const float*)d_in[28];
  const float* kb2 = (const float*)d_in[29];
  const float* q2  = (const float*)d_in[30];

  const int NP = in_sizes[0] / DIN;
  const int NA = in_sizes[1] / DIN;
  const int E  = in_sizes[2] / 2;
  (void)n_in; (void)out_size; (void)ws_size;

  const int nblocks = (E + BE - 1) / BE;
  const int NBp = (NP + DPB - 1) >> LOGD;
  const int NBa = (NA + DPB - 1) >> LOGD;
  const int NBmax = NBp > NBa ? NBp : NBa;
  const int nmx  = NP > NA ? NP : NA;
  const int nmx1 = nmx + 1;

  float* w = (float*)d_ws;
  size_t off_ = 0;
  auto A = [&](size_t n) { float* p = w + off_; off_ += (n + 15) & ~(size_t)15; return p; };
  float* XP_P1 = A((size_t)NP * 8);
  float* XP_A1 = A((size_t)NA * 8);
  float* RECPP = A((size_t)NP * 8);   // 32B bf16 records; reused as REC2P (16B, stride 4)
  float* RECPA = A((size_t)NP * 8);
  float* RECAP = A((size_t)NA * 8);   // reused as REC2A
  float* AD_PP = A((size_t)NP * 2);
  float* AD_PA = A((size_t)NA * 2);
  float* AD_AP = A((size_t)NP * 2);
  float* A2DPP = A((size_t)NP);
  float* A2DAP = A((size_t)NP);
  float* O_PP  = A((size_t)NP * 8);   // reused as O2PP
  float* O_PA  = A((size_t)NA * 8);
  float* O_AP  = A((size_t)NP * 8);   // reused as O2AP
  float* ATT1  = A(2);
  float* ATT2  = A(2);
  float* RED1  = A(16);
  float* RED2  = A(16);
  int* PART   = (int*)A((size_t)3 * E);                    // per-type; sorted in place by k_sort
  int* PB1    = (int*)A((size_t)3 * NBCAP * nblocks);      // row stride NBCAP
  int* TOTS   = (int*)A((size_t)3 * NBmax);
  int* BSTART = (int*)A((size_t)3 * (NBmax + 1));
  int* OFFs   = (int*)A((size_t)3 * nmx1);                 // CSR offsets per type

  float* REC2P = RECPP;
  float* REC2A = RECAP;
  float* O2PP  = O_PP;
  float* O2AP  = O_AP;

  hipMemsetAsync(RED1, 0, 32 * sizeof(float), stream);  // RED1+RED2 contiguous

  dim3 B(256);
  int nbP = (NP + 255) / 256, nbA = (NA + 255) / 256;
  int gG = (nmx * 32 + 511) / 512;                       // gather1 blocks per type (32 lanes/dst)
  int g1blocks = 8 * ((gG + 1) / 2);                     // type->XCD swizzled 1-D grid

  // layer 1 projections + packed bf16 source records + dst alphas
  k_proj1<<<(NP + 31) / 32, B, 0, stream>>>(x_p, w1p, b1p, XP_P1, NP);
  k_proj1<<<(NA + 31) / 32, B, 0, stream>>>(x_a, w1a, b1a, XP_A1, NA);
  k_pack1<<<nbP, B, 0, stream>>>(XP_P1, NP,
      as1pp, RECPP, as1pa, RECPA, ad1pp, AD_PP, ad1ap, AD_AP);
  k_pack1<<<nbA, B, 0, stream>>>(XP_A1, NA,
      as1ap, RECAP, nullptr, nullptr, ad1pa, AD_PA, nullptr, nullptr);

  // bucket partition + per-bucket dst sort -> full CSR (type order: pp, pa, ap)
  k_bcount<<<dim3(nblocks, 3), dim3(512), 0, stream>>>(
      eipp + E, eipa + E, eiap + E, E, nblocks, PB1);
  k_bscan<<<dim3(NBmax, 3), dim3(512), 0, stream>>>(
      PB1, TOTS, nblocks, NBmax, NBp, NBa, NBp);
  k_bstart<<<3, dim3(512), 0, stream>>>(TOTS, BSTART, NBmax, NBp, NBa, NBp);
  k_bplace<<<dim3(nblocks, 3), dim3(512), 0, stream>>>(
      eipp, eipa, eiap, E, nblocks, NBmax, NBp, NBa, NBp, PB1, BSTART, PART);
  k_sort<<<dim3(NBmax, 3), dim3(512), 0, stream>>>(
      PART, BSTART, NBmax, E, NBp, NBa, NBp, NP, NA, NP, nmx1, OFFs);

  // layer-1 CSR gathers (bf16 records, type->XCD swizzle, 32 lanes/dst, no atomics)
  k_gather1<<<dim3(g1blocks), dim3(512), 0, stream>>>(
      PART, OFFs, nmx1, E, gG,
      RECPP, AD_PP, O_PP, NP,
      RECPA, AD_PA, O_PA, NA,
      RECAP, AD_AP, O_AP, NP);

  // layer 1 semantic attention (paper: T=2; author: T=1 -> O_PA passes through)
  k_red<<<dim3(256, 2), B, 0, stream>>>(O_PP, O_AP, NP, 8, kw1, kb1, RED1, RED1 + 8);
  k_attn<<<1, 1, 0, stream>>>(RED1, q1, 2, 8, 1.0f / NP, ATT1);

  // layer 2 projections (paper: fused semantic combine; author: passthrough) + packed records
  k_proj2<<<nbP, B, 0, stream>>>(O_PP, O_AP, ATT1, NP, w2p, b2p,
      REC2P, as2pp, ad2pp, A2DPP, ad2ap, A2DAP);
  k_proj2<<<nbA, B, 0, stream>>>(O_PA, nullptr, nullptr, NA, w2a, b2a,
      REC2A, as2ap, nullptr, nullptr, nullptr, nullptr);

  // layer-2 CSR gathers (pp and ap; author layer-2 output is dead)
  k_gather2<<<dim3((NP * 16 + 511) / 512, 2), dim3(512), 0, stream>>>(
      PART, OFFs, nmx1, E, 0, 2,
      REC2P, A2DPP, O2PP,
      REC2A, A2DAP, O2AP, NP);

  // layer 2 semantic attention + final log_softmax
  k_red<<<dim3(256, 2), B, 0, stream>>>(O2PP, O2AP, NP, 7, kw2, kb2, RED2, RED2 + 7);
  k_attn<<<1, 1, 0, stream>>>(RED2, q2, 2, 7, 1.0f / NP, ATT2);
  k_final<<<nbP, B, 0, stream>>>(O2PP, O2AP, ATT2, (float*)d_out, NP);
}

// Round 16
// 307.129 us; speedup vs baseline: 1.1171x; 1.1171x over previous
//
#include <hip/hip_runtime.h>

constexpr int DIN = 128, HIDF = 8;
constexpr int LOGD = 8, DPB = 1 << LOGD;    // dsts per bucket (256)
constexpr int BE = 8192;                     // edges per partition block
constexpr int NBCAP = 512;                   // max buckets (N <= 128K); PB1 row stride
constexpr int SCAP = 16384;                  // sort LDS capacity

// ---- bf16 pack/unpack helpers (RNE) ----
__device__ inline unsigned bfpack(float lo, float hi) {
  unsigned a = __float_as_uint(lo), b = __float_as_uint(hi);
  unsigned ra = (a + 0x7fffu + ((a >> 16) & 1u)) >> 16;
  unsigned rb = (b + 0x7fffu + ((b >> 16) & 1u)) >> 16;
  return ra | (rb << 16);
}
__device__ inline float bflo(unsigned u) { return __uint_as_float(u << 16); }
__device__ inline float bfhi(unsigned u) { return __uint_as_float(u & 0xffff0000u); }

// ---------------- layer-1 projection: xp[N,8] = x[N,128] @ w[128,8] + b ----------------
__global__ __launch_bounds__(256) void k_proj1(
    const float* __restrict__ x, const float* __restrict__ w,
    const float* __restrict__ b, float* __restrict__ xp, int N)
{
  __shared__ float ws_[DIN * HIDF];
  __shared__ float xs[32 * 132];
  int t = threadIdx.x;
  ((float4*)ws_)[t] = ((const float4*)w)[t];
  int base = blockIdx.x * 32;
#pragma unroll
  for (int i = 0; i < 4; i++) {
    int f4 = t + i * 256;
    int nl = f4 >> 5;
    if (base + nl < N) {
      float4 v = ((const float4*)(x + (size_t)base * DIN))[f4];
      int col = (f4 & 31) << 2;
      *((float4*)&xs[nl * 132 + col]) = v;
    }
  }
  __syncthreads();
  int nl = t >> 3, j = t & 7;
  int n0 = base + nl;
  if (n0 >= N) return;
  float acc = b[j];
  const float* xr = &xs[nl * 132];
#pragma unroll 8
  for (int k = 0; k < DIN; k++) acc = fmaf(xr[k], ws_[k * HIDF + j], acc);
  xp[(size_t)n0 * HIDF + j] = acc;
}

// -- layer-1 pack: per-type 32B records {bf16 xp[8] (16B), f32 a0,a1 (8B), pad} + dst alphas --
__global__ __launch_bounds__(256) void k_pack1(
    const float* __restrict__ xp, int N,
    const float* __restrict__ ps0, float* __restrict__ rec0,
    const float* __restrict__ ps1, float* __restrict__ rec1,
    const float* __restrict__ pd0, float* __restrict__ od0,
    const float* __restrict__ pd1, float* __restrict__ od1)
{
  int n = blockIdx.x * blockDim.x + threadIdx.x;
  if (n >= N) return;
  float4 a4 = ((const float4*)xp)[(size_t)n * 2];
  float4 b4 = ((const float4*)xp)[(size_t)n * 2 + 1];
  float xv[8] = {a4.x, a4.y, a4.z, a4.w, b4.x, b4.y, b4.z, b4.w};
  uint4 pk;
  pk.x = bfpack(xv[0], xv[1]); pk.y = bfpack(xv[2], xv[3]);
  pk.z = bfpack(xv[4], xv[5]); pk.w = bfpack(xv[6], xv[7]);
#define DOT2(p, s0, s1)                                               \
  float s0 = 0.f, s1 = 0.f;                                           \
  for (int d = 0; d < 4; d++) { s0 += xv[d] * p[d]; s1 += xv[4 + d] * p[4 + d]; }
  if (rec0) {
    DOT2(ps0, s0, s1)
    ((uint4*)rec0)[(size_t)n * 2] = pk;
    ((float4*)rec0)[(size_t)n * 2 + 1] = make_float4(s0, s1, 0.f, 0.f);
  }
  if (rec1) {
    DOT2(ps1, s0, s1)
    ((uint4*)rec1)[(size_t)n * 2] = pk;
    ((float4*)rec1)[(size_t)n * 2 + 1] = make_float4(s0, s1, 0.f, 0.f);
  }
  if (pd0) { DOT2(pd0, s0, s1) ((float2*)od0)[n] = make_float2(s0, s1); }
  if (pd1) { DOT2(pd1, s0, s1) ((float2*)od1)[n] = make_float2(s0, s1); }
#undef DOT2
}

// ---------------- partition pass 1: per-(block,bucket) coarse histogram ----------------
__global__ __launch_bounds__(512) void k_bcount(
    const int* __restrict__ d0, const int* __restrict__ d1, const int* __restrict__ d2,
    int E, int nblocks, int* __restrict__ PB1)
{
  int ty = blockIdx.y;
  const int* dst = ty == 0 ? d0 : (ty == 1 ? d1 : d2);
  __shared__ int hist[NBCAP];
  int t = threadIdx.x;
  hist[t] = 0;
  __syncthreads();
  int blk = blockIdx.x;
  int e0 = blk * BE, e1 = min(E, e0 + BE);
  int qbase = e0 >> 2, nq = (e1 - e0) >> 2;
#pragma unroll
  for (int i = 0; i < 4; i++) {
    int q = i * 512 + t;
    if (q < nq) {
      int4 v = ((const int4*)dst)[qbase + q];
      atomicAdd(&hist[v.x >> LOGD], 1);
      atomicAdd(&hist[v.y >> LOGD], 1);
      atomicAdd(&hist[v.z >> LOGD], 1);
      atomicAdd(&hist[v.w >> LOGD], 1);
    }
  }
  __syncthreads();
  PB1[((size_t)(ty * NBCAP) + t) * nblocks + blk] = hist[t];
}

// ---------------- partition pass 2: scan per-bucket block counts (in place) ----------------
__global__ __launch_bounds__(512) void k_bscan(
    int* __restrict__ PB1, int* __restrict__ TOTS,
    int nblocks, int NBmax, int nb0, int nb1, int nb2)
{
  int ty = blockIdx.y;
  int NBt = ty == 0 ? nb0 : (ty == 1 ? nb1 : nb2);
  int bk = blockIdx.x;
  if (bk >= NBt) return;
  int* p = PB1 + ((size_t)(ty * NBCAP) + bk) * nblocks;
  int t = threadIdx.x;
  int v = (t < nblocks) ? p[t] : 0;
  int lane = t & 63, wv = t >> 6;
  int x = v;
#pragma unroll
  for (int o = 1; o < 64; o <<= 1) { int u = __shfl_up(x, o, 64); if (lane >= o) x += u; }
  __shared__ int ws[8];
  if (lane == 63) ws[wv] = x;
  __syncthreads();
  if (t == 0) { int s = 0; for (int k = 0; k < 8; k++) { int tmp = ws[k]; ws[k] = s; s += tmp; } }
  __syncthreads();
  int excl = x - v + ws[wv];
  if (t < nblocks) p[t] = excl;
  if (t == nblocks - 1) TOTS[ty * NBmax + bk] = excl + v;
}

// ---------------- partition pass 3: bucket start offsets (per type, within PART+ty*E) -------
__global__ __launch_bounds__(512) void k_bstart(
    const int* __restrict__ TOTS, int* __restrict__ BSTART,
    int NBmax, int nb0, int nb1, int nb2)
{
  int ty = blockIdx.x;
  int NBt = ty == 0 ? nb0 : (ty == 1 ? nb1 : nb2);
  int t = threadIdx.x;
  int v = (t < NBt) ? TOTS[ty * NBmax + t] : 0;
  int lane = t & 63, wv = t >> 6;
  int x = v;
#pragma unroll
  for (int o = 1; o < 64; o <<= 1) { int u = __shfl_up(x, o, 64); if (lane >= o) x += u; }
  __shared__ int ws[8];
  if (lane == 63) ws[wv] = x;
  __syncthreads();
  if (t == 0) { int s = 0; for (int k = 0; k < 8; k++) { int tmp = ws[k]; ws[k] = s; s += tmp; } }
  __syncthreads();
  int excl = x - v + ws[wv];
  int* bs = BSTART + (size_t)ty * (NBmax + 1);
  if (t < NBt) bs[t] = excl;
  if (t == NBt - 1) bs[NBt] = excl + v;
}

// ---- partition pass 4: LDS-staged bucket-partition (bkt-table write-out, no bin search) ----
__global__ __launch_bounds__(512) void k_bplace(
    const int* __restrict__ e0p, const int* __restrict__ e1p, const int* __restrict__ e2p,
    int E, int nblocks, int NBmax, int nb0, int nb1, int nb2,
    const int* __restrict__ PB1, const int* __restrict__ BSTART,
    int* __restrict__ PART)
{
  int ty = blockIdx.y;
  const int* src = ty == 0 ? e0p : (ty == 1 ? e1p : e2p);
  const int* dst = src + E;
  int NBt = ty == 0 ? nb0 : (ty == 1 ? nb1 : nb2);
  int* part = PART + (size_t)ty * E;
  __shared__ int hist[NBCAP];
  __shared__ int lscan[NBCAP + 1];
  __shared__ int base[NBCAP];   // bst + bpref - lscan, fused
  __shared__ int stage[BE];
  __shared__ short bkt[BE];
  __shared__ int ws[8];
  int t = threadIdx.x;
  hist[t] = 0;
  __syncthreads();
  int blk = blockIdx.x;
  int e0 = blk * BE, e1 = min(E, e0 + BE);
  int cnt = e1 - e0;
  int qbase = e0 >> 2, nq = cnt >> 2;
  int dreg[16], sreg[16];
  unsigned short lr[16];
#pragma unroll
  for (int i = 0; i < 4; i++) {
    int q = i * 512 + t;
    if (q < nq) {
      int4 dq = ((const int4*)dst)[qbase + q];
      int4 sq = ((const int4*)src)[qbase + q];
      dreg[i * 4 + 0] = dq.x; dreg[i * 4 + 1] = dq.y;
      dreg[i * 4 + 2] = dq.z; dreg[i * 4 + 3] = dq.w;
      sreg[i * 4 + 0] = sq.x; sreg[i * 4 + 1] = sq.y;
      sreg[i * 4 + 2] = sq.z; sreg[i * 4 + 3] = sq.w;
#pragma unroll
      for (int k = 0; k < 4; k++)
        lr[i * 4 + k] = (unsigned short)atomicAdd(&hist[dreg[i * 4 + k] >> LOGD], 1);
    } else {
#pragma unroll
      for (int k = 0; k < 4; k++) dreg[i * 4 + k] = -1;
    }
  }
  __syncthreads();
  // exclusive scan of 512 hist bins
  {
    int v = hist[t];
    int lane = t & 63, wv = t >> 6;
    int x = v;
#pragma unroll
    for (int o = 1; o < 64; o <<= 1) { int u = __shfl_up(x, o, 64); if (lane >= o) x += u; }
    if (lane == 63) ws[wv] = x;
    __syncthreads();
    if (t == 0) { int s = 0; for (int k = 0; k < 8; k++) { int tmp = ws[k]; ws[k] = s; s += tmp; } }
    __syncthreads();
    int excl = x - v + ws[wv];
    lscan[t] = excl;
    if (t == NBCAP - 1) lscan[NBCAP] = excl + v;
  }
  if (t < NBt)
    base[t] = BSTART[(size_t)ty * (NBmax + 1) + t]
            + PB1[((size_t)(ty * NBCAP) + t) * nblocks + blk];
  __syncthreads();
  // fill bkt table: each thread handles its bucket's range
  {
    int b = t;
    if (b < NBt) {
      int j0 = lscan[b], j1 = lscan[b + 1];
      base[b] -= j0;                       // fuse: part index = base[b] + j
      for (int j = j0; j < j1; j++) bkt[j] = (short)b;
    }
  }
  // stage edges sorted by bucket
#pragma unroll
  for (int i = 0; i < 16; i++) {
    int d = dreg[i];
    if (d >= 0) {
      int bk2 = d >> LOGD;
      stage[lscan[bk2] + lr[i]] = (sreg[i] << LOGD) | (d & (DPB - 1));
    }
  }
  __syncthreads();
  for (int j = t; j < cnt; j += 512)
    part[base[bkt[j]] + j] = stage[j];
}

// ---- partition pass 5: per-bucket counting sort (single PART read, rank-capture) ----
__global__ __launch_bounds__(512) void k_sort(
    int* __restrict__ PART, const int* __restrict__ BSTART, int NBmax, int E,
    int nb0, int nb1, int nb2, int n0, int n1, int n2,
    int nmx1, int* __restrict__ OFFs)
{
  int ty = blockIdx.y;
  int NBt = ty == 0 ? nb0 : (ty == 1 ? nb1 : nb2);
  int Nt  = ty == 0 ? n0 : (ty == 1 ? n1 : n2);
  int bk = blockIdx.x;
  if (bk >= NBt) return;
  int* part = PART + (size_t)ty * E;
  const int* bs = BSTART + (size_t)ty * (NBmax + 1);
  int s0 = bs[bk], s1 = bs[bk + 1];
  int cnt = s1 - s0;
  __shared__ int hist[DPB];
  __shared__ int binoff[DPB];
  __shared__ int sorted[SCAP];
  __shared__ int ws[4];
  int t = threadIdx.x;
  if (t < DPB) hist[t] = 0;
  __syncthreads();
  int myv[32];
  unsigned short myr[32];
#pragma unroll
  for (int it = 0; it < 32; it++) {
    int j = s0 + it * 512 + t;
    if (j < s1) {
      int v = part[j];
      myv[it] = v;
      myr[it] = (unsigned short)atomicAdd(&hist[v & (DPB - 1)], 1);
    } else myv[it] = -1;
  }
  __syncthreads();
  {
    int v = (t < DPB) ? hist[t] : 0;
    int lane = t & 63, wv = t >> 6;
    int x = v;
#pragma unroll
    for (int o = 1; o < 64; o <<= 1) { int u = __shfl_up(x, o, 64); if (lane >= o) x += u; }
    if (t < DPB && lane == 63) ws[wv] = x;
    __syncthreads();
    if (t == 0) { int s = 0; for (int k = 0; k < 4; k++) { int tmp = ws[k]; ws[k] = s; s += tmp; } }
    __syncthreads();
    if (t < DPB) binoff[t] = x - v + ws[wv];
  }
  __syncthreads();
  int d0 = bk << LOGD;
  if (t < DPB && d0 + t < Nt) OFFs[(size_t)ty * nmx1 + d0 + t] = s0 + binoff[t];
  if (bk == NBt - 1 && t == 0) OFFs[(size_t)ty * nmx1 + Nt] = s1;
#pragma unroll
  for (int it = 0; it < 32; it++) {
    int v = myv[it];
    if (v >= 0) sorted[binoff[v & (DPB - 1)] + myr[it]] = v >> LOGD;
  }
  __syncthreads();
  for (int j = t; j < cnt; j += 512) part[s0 + j] = sorted[j];
}

// -- layer-1 gather: CSR, 16 lanes/dst, bf16 records, type->XCD swizzle, reg accumulate --
__global__ __launch_bounds__(512) void k_gather1(
    const int* __restrict__ PART, const int* __restrict__ OFFs, int nmx1, int E, int gG,
    const float* __restrict__ r0, const float* __restrict__ ad0, float* __restrict__ o0, int n0,
    const float* __restrict__ r1, const float* __restrict__ ad1, float* __restrict__ o1, int n1,
    const float* __restrict__ r2, const float* __restrict__ ad2, float* __restrict__ o2, int n2)
{
  int bid = blockIdx.x;
  int rr = bid & 7, m = bid >> 3;
  int ty, xb;
  if (rr < 3)      { ty = 0; xb = m * 3 + rr; }
  else if (rr < 6) { ty = 1; xb = m * 3 + (rr - 3); }
  else             { ty = 2; xb = m * 2 + (rr - 6); }
  if (xb >= gG) return;
  const float* rec = ty == 0 ? r0 : (ty == 1 ? r1 : r2);
  const float* ad_ = ty == 0 ? ad0 : (ty == 1 ? ad1 : ad2);
  float* out = ty == 0 ? o0 : (ty == 1 ? o1 : o2);
  int Nt = ty == 0 ? n0 : (ty == 1 ? n1 : n2);
  int g = xb * 512 + threadIdx.x;
  int d = g >> 4, l = g & 15;                // 16 lanes per dst
  if (d >= Nt) return;
  const int* off = OFFs + (size_t)ty * nmx1;
  const int* part = PART + (size_t)ty * E;
  int i0 = off[d], i1 = off[d + 1];
  float2 adv = ((const float2*)ad_)[d];
  float s0 = 0.f, s1 = 0.f;
  float acc[8] = {0.f, 0.f, 0.f, 0.f, 0.f, 0.f, 0.f, 0.f};
  for (int i = i0 + l; i < i1; i += 16) {
    int s = part[i];
    uint4 q = ((const uint4*)rec)[(size_t)s * 2];
    float4 ax = ((const float4*)rec)[(size_t)s * 2 + 1];
    float a0 = ax.x + adv.x; a0 = a0 > 0.f ? a0 : 0.2f * a0;
    float a1 = ax.y + adv.y; a1 = a1 > 0.f ? a1 : 0.2f * a1;
    float e0 = __expf(a0), e1 = __expf(a1);
    s0 += e0; s1 += e1;
    acc[0] += e0 * bflo(q.x); acc[1] += e0 * bfhi(q.x);
    acc[2] += e0 * bflo(q.y); acc[3] += e0 * bfhi(q.y);
    acc[4] += e1 * bflo(q.z); acc[5] += e1 * bfhi(q.z);
    acc[6] += e1 * bflo(q.w); acc[7] += e1 * bfhi(q.w);
  }
#pragma unroll
  for (int mm = 1; mm < 16; mm <<= 1) {
    s0 += __shfl_xor(s0, mm, 16);
    s1 += __shfl_xor(s1, mm, 16);
#pragma unroll
    for (int k = 0; k < 8; k++) acc[k] += __shfl_xor(acc[k], mm, 16);
  }
  if (l) return;
  float r0i = 1.f / (s0 + 1e-16f), r1i = 1.f / (s1 + 1e-16f);
  float4 q0 = make_float4(fmaxf(acc[0] * r0i, 0.f), fmaxf(acc[1] * r0i, 0.f),
                          fmaxf(acc[2] * r0i, 0.f), fmaxf(acc[3] * r0i, 0.f));
  float4 q1 = make_float4(fmaxf(acc[4] * r1i, 0.f), fmaxf(acc[5] * r1i, 0.f),
                          fmaxf(acc[6] * r1i, 0.f), fmaxf(acc[7] * r1i, 0.f));
  ((float4*)out)[(size_t)d * 2] = q0;
  ((float4*)out)[(size_t)d * 2 + 1] = q1;
}

// ------- layer-2 gather: CSR, 16 lanes/dst, 16B bf16 records, reg accumulate -------
__global__ __launch_bounds__(512) void k_gather2(
    const int* __restrict__ PART, const int* __restrict__ OFFs, int nmx1, int E,
    int ti0, int ti1,
    const float* __restrict__ r0, const float* __restrict__ ad0, float* __restrict__ o0,
    const float* __restrict__ r1, const float* __restrict__ ad1, float* __restrict__ o1, int N)
{
  int zz = blockIdx.y;
  int ty = zz == 0 ? ti0 : ti1;
  const float* rec = zz == 0 ? r0 : r1;
  const float* ad_ = zz == 0 ? ad0 : ad1;
  float* out = zz == 0 ? o0 : o1;
  int g = blockIdx.x * 512 + threadIdx.x;
  int d = g >> 4, l = g & 15;
  if (d >= N) return;
  const int* off = OFFs + (size_t)ty * nmx1;
  const int* part = PART + (size_t)ty * E;
  int i0 = off[d], i1 = off[d + 1];
  float adv = ad_[d];
  float ssum = 0.f;
  float acc[7] = {0.f, 0.f, 0.f, 0.f, 0.f, 0.f, 0.f};
  for (int i = i0 + l; i < i1; i += 16) {
    int s = part[i];
    uint4 q = ((const uint4*)rec)[s];
    float a = bfhi(q.w) + adv; a = a > 0.f ? a : 0.2f * a;
    float ex = __expf(a);
    ssum += ex;
    acc[0] += ex * bflo(q.x); acc[1] += ex * bfhi(q.x);
    acc[2] += ex * bflo(q.y); acc[3] += ex * bfhi(q.y);
    acc[4] += ex * bflo(q.z); acc[5] += ex * bfhi(q.z);
    acc[6] += ex * bflo(q.w);
  }
#pragma unroll
  for (int mm = 1; mm < 16; mm <<= 1) {
    ssum += __shfl_xor(ssum, mm, 16);
#pragma unroll
    for (int k = 0; k < 7; k++) acc[k] += __shfl_xor(acc[k], mm, 16);
  }
  if (l) return;
  float r = 1.f / (ssum + 1e-16f);
  float4 q0 = make_float4(fmaxf(acc[0] * r, 0.f), fmaxf(acc[1] * r, 0.f),
                          fmaxf(acc[2] * r, 0.f), fmaxf(acc[3] * r, 0.f));
  float4 q1 = make_float4(fmaxf(acc[4] * r, 0.f), fmaxf(acc[5] * r, 0.f),
                          fmaxf(acc[6] * r, 0.f), 0.f);
  ((float4*)out)[(size_t)d * 2] = q0;
  ((float4*)out)[(size_t)d * 2 + 1] = q1;
}

// ---------------- semantic-attention reduction (batched over 2 inputs) ----------------
__global__ __launch_bounds__(256) void k_red(
    const float* __restrict__ hA, const float* __restrict__ hB, int N, int F,
    const float* __restrict__ kw, const float* __restrict__ kb,
    float* __restrict__ redA, float* __restrict__ redB)
{
  const float* h = blockIdx.y ? hB : hA;
  float* red = blockIdx.y ? redB : redA;
  __shared__ float kws[64], kbs[8];
  __shared__ float sm[256 * 8];
  int t = threadIdx.x;
  if (t < F * F) kws[t] = kw[t];
  if (t < F) kbs[t] = kb[t];
  __syncthreads();
  float acc[8] = {0, 0, 0, 0, 0, 0, 0, 0};
  for (int n = blockIdx.x * 256 + t; n < N; n += gridDim.x * 256) {
    const float* row = h + (size_t)n * 8;
    float xv[8];
    for (int k = 0; k < F; k++) xv[k] = row[k];
    for (int f = 0; f < F; f++) {
      float s = kbs[f];
      for (int k = 0; k < F; k++) s += xv[k] * kws[k * F + f];
      acc[f] += tanhf(s);
    }
  }
  for (int f = 0; f < 8; f++) sm[t * 8 + f] = (f < F) ? acc[f] : 0.f;
  __syncthreads();
  for (int s2 = 128; s2 > 0; s2 >>= 1) {
    if (t < s2)
      for (int f = 0; f < 8; f++) sm[t * 8 + f] += sm[(t + s2) * 8 + f];
    __syncthreads();
  }
  if (t < F) atomicAdd(&red[t], sm[t]);
}

// ---------------- semantic attention weights (tiny) ----------------
__global__ void k_attn(const float* __restrict__ red, const float* __restrict__ q,
                       int T, int F, float invN, float* __restrict__ attn)
{
  if (threadIdx.x != 0 || blockIdx.x != 0) return;
  float v[4]; float m = -1e30f;
  for (int t2 = 0; t2 < T; t2++) {
    float s = 0.f;
    for (int f = 0; f < F; f++) s += q[f] * red[t2 * F + f];
    s *= invN;
    v[t2] = s; m = fmaxf(m, s);
  }
  float sum = 0.f;
  for (int t2 = 0; t2 < T; t2++) { v[t2] = __expf(v[t2] - m); sum += v[t2]; }
  for (int t2 = 0; t2 < T; t2++) attn[t2] = v[t2] / sum;
}

// -- layer-2 projection: fused semantic combine (+relu) + packed 16B bf16 record + dst alphas --
__global__ __launch_bounds__(256) void k_proj2(
    const float* __restrict__ h0, const float* __restrict__ h1,
    const float* __restrict__ attn, int N,
    const float* __restrict__ w, const float* __restrict__ b,
    float* __restrict__ rec2, const float* __restrict__ psrc,
    const float* __restrict__ pd0, float* __restrict__ od0,
    const float* __restrict__ pd1, float* __restrict__ od1)
{
  int n = blockIdx.x * blockDim.x + threadIdx.x;
  if (n >= N) return;
  float a0 = 1.f, a1 = 0.f;
  if (attn) { a0 = attn[0]; a1 = attn[1]; }
  float4 u0 = ((const float4*)h0)[(size_t)n * 2];
  float4 u1 = ((const float4*)h0)[(size_t)n * 2 + 1];
  float xv[8] = {u0.x, u0.y, u0.z, u0.w, u1.x, u1.y, u1.z, u1.w};
  if (h1) {
    float4 v0 = ((const float4*)h1)[(size_t)n * 2];
    float4 v1 = ((const float4*)h1)[(size_t)n * 2 + 1];
    float yv[8] = {v0.x, v0.y, v0.z, v0.w, v1.x, v1.y, v1.z, v1.w};
    for (int j = 0; j < 8; j++) xv[j] = a0 * xv[j] + a1 * yv[j];
  }
  for (int j = 0; j < 8; j++) xv[j] = fmaxf(xv[j], 0.f);
  float y[7];
  for (int j = 0; j < 7; j++) y[j] = b[j];
  for (int k = 0; k < 8; k++) {
    float xk = xv[k];
    for (int j = 0; j < 7; j++) y[j] += xk * w[k * 7 + j];
  }
  float ssrc = 0.f;
  for (int j = 0; j < 7; j++) ssrc += y[j] * psrc[j];
  uint4 pk;
  pk.x = bfpack(y[0], y[1]); pk.y = bfpack(y[2], y[3]);
  pk.z = bfpack(y[4], y[5]); pk.w = bfpack(y[6], ssrc);
  ((uint4*)rec2)[n] = pk;
#define DOD(p, o)                                       \
  if (p) {                                              \
    float s = 0.f;                                      \
    for (int j = 0; j < 7; j++) s += y[j] * p[j];       \
    o[n] = s;                                           \
  }
  DOD(pd0, od0) DOD(pd1, od1)
#undef DOD
}

// ---------------- final combine + log_softmax ----------------
__global__ __launch_bounds__(256) void k_final(
    const float* __restrict__ h0, const float* __restrict__ h1,
    const float* __restrict__ attn, float* __restrict__ out, int N)
{
  int n = blockIdx.x * blockDim.x + threadIdx.x;
  if (n >= N) return;
  float a0 = attn[0], a1 = attn[1];
  const float* r0 = h0 + (size_t)n * 8;
  const float* r1 = h1 + (size_t)n * 8;
  float v[7]; float m = -1e30f;
  for (int c = 0; c < 7; c++) { float t = a0 * r0[c] + a1 * r1[c]; v[c] = t; m = fmaxf(m, t); }
  float sum = 0.f;
  for (int c = 0; c < 7; c++) sum += __expf(v[c] - m);
  float lse = m + logf(sum);
  for (int c = 0; c < 7; c++) out[(size_t)n * 7 + c] = v[c] - lse;
}

extern "C" void kernel_launch(void* const* d_in, const int* in_sizes, int n_in,
                              void* d_out, int out_size, void* d_ws, size_t ws_size,
                              hipStream_t stream)
{
  const float* x_p  = (const float*)d_in[0];
  const float* x_a  = (const float*)d_in[1];
  const int*   eipp = (const int*)d_in[2];
  const int*   eipa = (const int*)d_in[3];
  const int*   eiap = (const int*)d_in[4];
  const float* w1p  = (const float*)d_in[5];
  const float* b1p  = (const float*)d_in[6];
  const float* w1a  = (const float*)d_in[7];
  const float* b1a  = (const float*)d_in[8];
  const float* as1pp = (const float*)d_in[9];
  const float* ad1pp = (const float*)d_in[10];
  const float* as1pa = (const float*)d_in[11];
  const float* ad1pa = (const float*)d_in[12];
  const float* as1ap = (const float*)d_in[13];
  const float* ad1ap = (const float*)d_in[14];
  const float* kw1 = (const float*)d_in[15];
  const float* kb1 = (const float*)d_in[16];
  const float* q1  = (const float*)d_in[17];
  const float* w2p = (const float*)d_in[18];
  const float* b2p = (const float*)d_in[19];
  const float* w2a = (const float*)d_in[20];
  const float* b2a = (const float*)d_in[21];
  const float* as2pp = (const float*)d_in[22];
  const float* ad2pp = (const float*)d_in[23];
  // d_in[24]=as2pa, d_in[25]=ad2pa unused: pa edges only feed author nodes,
  // and author layer-2 output is dead (final output is papers only).
  const float* as2ap = (const float*)d_in[26];
  const float* ad2ap = (const float*)d_in[27];
  const float* kw2 = (const float*)d_in[28];
  const float* kb2 = (const float*)d_in[29];
  const float* q2  = (const float*)d_in[30];

  const int NP = in_sizes[0] / DIN;
  const int NA = in_sizes[1] / DIN;
  const int E  = in_sizes[2] / 2;
  (void)n_in; (void)out_size; (void)ws_size;

  const int nblocks = (E + BE - 1) / BE;
  const int NBp = (NP + DPB - 1) >> LOGD;
  const int NBa = (NA + DPB - 1) >> LOGD;
  const int NBmax = NBp > NBa ? NBp : NBa;
  const int nmx  = NP > NA ? NP : NA;
  const int nmx1 = nmx + 1;

  float* w = (float*)d_ws;
  size_t off_ = 0;
  auto A = [&](size_t n) { float* p = w + off_; off_ += (n + 15) & ~(size_t)15; return p; };
  float* XP_P1 = A((size_t)NP * 8);
  float* XP_A1 = A((size_t)NA * 8);
  float* RECPP = A((size_t)NP * 8);   // 32B bf16 records; reused as REC2P (16B, stride 4)
  float* RECPA = A((size_t)NP * 8);
  float* RECAP = A((size_t)NA * 8);   // reused as REC2A
  float* AD_PP = A((size_t)NP * 2);
  float* AD_PA = A((size_t)NA * 2);
  float* AD_AP = A((size_t)NP * 2);
  float* A2DPP = A((size_t)NP);
  float* A2DAP = A((size_t)NP);
  float* O_PP  = A((size_t)NP * 8);   // reused as O2PP
  float* O_PA  = A((size_t)NA * 8);
  float* O_AP  = A((size_t)NP * 8);   // reused as O2AP
  float* ATT1  = A(2);
  float* ATT2  = A(2);
  float* RED1  = A(16);
  float* RED2  = A(16);
  int* PART   = (int*)A((size_t)3 * E);                    // per-type; sorted in place by k_sort
  int* PB1    = (int*)A((size_t)3 * NBCAP * nblocks);      // row stride NBCAP
  int* TOTS   = (int*)A((size_t)3 * NBmax);
  int* BSTART = (int*)A((size_t)3 * (NBmax + 1));
  int* OFFs   = (int*)A((size_t)3 * nmx1);                 // CSR offsets per type

  float* REC2P = RECPP;
  float* REC2A = RECAP;
  float* O2PP  = O_PP;
  float* O2AP  = O_AP;

  hipMemsetAsync(RED1, 0, 32 * sizeof(float), stream);  // RED1+RED2 contiguous

  dim3 B(256);
  int nbP = (NP + 255) / 256, nbA = (NA + 255) / 256;
  int gG = (nmx * 16 + 511) / 512;                       // gather1 blocks per type (16 lanes/dst)
  int g1blocks = 8 * ((gG + 1) / 2);                     // type->XCD swizzled 1-D grid

  // layer 1 projections + packed bf16 source records + dst alphas
  k_proj1<<<(NP + 31) / 32, B, 0, stream>>>(x_p, w1p, b1p, XP_P1, NP);
  k_proj1<<<(NA + 31) / 32, B, 0, stream>>>(x_a, w1a, b1a, XP_A1, NA);
  k_pack1<<<nbP, B, 0, stream>>>(XP_P1, NP,
      as1pp, RECPP, as1pa, RECPA, ad1pp, AD_PP, ad1ap, AD_AP);
  k_pack1<<<nbA, B, 0, stream>>>(XP_A1, NA,
      as1ap, RECAP, nullptr, nullptr, ad1pa, AD_PA, nullptr, nullptr);

  // bucket partition + per-bucket dst sort -> full CSR (type order: pp, pa, ap)
  k_bcount<<<dim3(nblocks, 3), dim3(512), 0, stream>>>(
      eipp + E, eipa + E, eiap + E, E, nblocks, PB1);
  k_bscan<<<dim3(NBmax, 3), dim3(512), 0, stream>>>(
      PB1, TOTS, nblocks, NBmax, NBp, NBa, NBp);
  k_bstart<<<3, dim3(512), 0, stream>>>(TOTS, BSTART, NBmax, NBp, NBa, NBp);
  k_bplace<<<dim3(nblocks, 3), dim3(512), 0, stream>>>(
      eipp, eipa, eiap, E, nblocks, NBmax, NBp, NBa, NBp, PB1, BSTART, PART);
  k_sort<<<dim3(NBmax, 3), dim3(512), 0, stream>>>(
      PART, BSTART, NBmax, E, NBp, NBa, NBp, NP, NA, NP, nmx1, OFFs);

  // layer-1 CSR gathers (bf16 records, type->XCD swizzle, 16 lanes/dst, no atomics)
  k_gather1<<<dim3(g1blocks), dim3(512), 0, stream>>>(
      PART, OFFs, nmx1, E, gG,
      RECPP, AD_PP, O_PP, NP,
      RECPA, AD_PA, O_PA, NA,
      RECAP, AD_AP, O_AP, NP);

  // layer 1 semantic attention (paper: T=2; author: T=1 -> O_PA passes through)
  k_red<<<dim3(256, 2), B, 0, stream>>>(O_PP, O_AP, NP, 8, kw1, kb1, RED1, RED1 + 8);
  k_attn<<<1, 1, 0, stream>>>(RED1, q1, 2, 8, 1.0f / NP, ATT1);

  // layer 2 projections (paper: fused semantic combine; author: passthrough) + packed records
  k_proj2<<<nbP, B, 0, stream>>>(O_PP, O_AP, ATT1, NP, w2p, b2p,
      REC2P, as2pp, ad2pp, A2DPP, ad2ap, A2DAP);
  k_proj2<<<nbA, B, 0, stream>>>(O_PA, nullptr, nullptr, NA, w2a, b2a,
      REC2A, as2ap, nullptr, nullptr, nullptr, nullptr);

  // layer-2 CSR gathers (pp and ap; author layer-2 output is dead)
  k_gather2<<<dim3((NP * 16 + 511) / 512, 2), dim3(512), 0, stream>>>(
      PART, OFFs, nmx1, E, 0, 2,
      REC2P, A2DPP, O2PP,
      REC2A, A2DAP, O2AP, NP);

  // layer 2 semantic attention + final log_softmax
  k_red<<<dim3(256, 2), B, 0, stream>>>(O2PP, O2AP, NP, 7, kw2, kb2, RED2, RED2 + 7);
  k_attn<<<1, 1, 0, stream>>>(RED2, q2, 2, 7, 1.0f / NP, ATT2);
  k_final<<<nbP, B, 0, stream>>>(O2PP, O2AP, ATT2, (float*)d_out, NP);
}

// Round 17
// 282.625 us; speedup vs baseline: 1.2139x; 1.0867x over previous
//
#include <hip/hip_runtime.h>

constexpr int DIN = 128, HIDF = 8;
constexpr int LOGD = 8, DPB = 1 << LOGD;    // dsts per bucket (256)
constexpr int BE = 8192;                     // edges per partition block
constexpr int NBCAP = 512;                   // max buckets per type (N <= 128K)
constexpr int CAP = 12288;                   // fixed per-bucket slot capacity (mean 8192 + 45 sigma)

// ---- bf16 pack/unpack helpers (RNE) ----
__device__ inline unsigned bfpack(float lo, float hi) {
  unsigned a = __float_as_uint(lo), b = __float_as_uint(hi);
  unsigned ra = (a + 0x7fffu + ((a >> 16) & 1u)) >> 16;
  unsigned rb = (b + 0x7fffu + ((b >> 16) & 1u)) >> 16;
  return ra | (rb << 16);
}
__device__ inline float bflo(unsigned u) { return __uint_as_float(u << 16); }
__device__ inline float bfhi(unsigned u) { return __uint_as_float(u & 0xffff0000u); }

// ---------------- layer-1 projection: xp[N,8] = x[N,128] @ w[128,8] + b ----------------
__global__ __launch_bounds__(256) void k_proj1(
    const float* __restrict__ x, const float* __restrict__ w,
    const float* __restrict__ b, float* __restrict__ xp, int N)
{
  __shared__ float ws_[DIN * HIDF];
  __shared__ float xs[32 * 132];
  int t = threadIdx.x;
  ((float4*)ws_)[t] = ((const float4*)w)[t];
  int base = blockIdx.x * 32;
#pragma unroll
  for (int i = 0; i < 4; i++) {
    int f4 = t + i * 256;
    int nl = f4 >> 5;
    if (base + nl < N) {
      float4 v = ((const float4*)(x + (size_t)base * DIN))[f4];
      int col = (f4 & 31) << 2;
      *((float4*)&xs[nl * 132 + col]) = v;
    }
  }
  __syncthreads();
  int nl = t >> 3, j = t & 7;
  int n0 = base + nl;
  if (n0 >= N) return;
  float acc = b[j];
  const float* xr = &xs[nl * 132];
#pragma unroll 8
  for (int k = 0; k < DIN; k++) acc = fmaf(xr[k], ws_[k * HIDF + j], acc);
  xp[(size_t)n0 * HIDF + j] = acc;
}

// -- layer-1 pack: per-type 32B records {bf16 xp[8] (16B), f32 a0,a1 (8B), pad} + dst alphas --
__global__ __launch_bounds__(256) void k_pack1(
    const float* __restrict__ xp, int N,
    const float* __restrict__ ps0, float* __restrict__ rec0,
    const float* __restrict__ ps1, float* __restrict__ rec1,
    const float* __restrict__ pd0, float* __restrict__ od0,
    const float* __restrict__ pd1, float* __restrict__ od1)
{
  int n = blockIdx.x * blockDim.x + threadIdx.x;
  if (n >= N) return;
  float4 a4 = ((const float4*)xp)[(size_t)n * 2];
  float4 b4 = ((const float4*)xp)[(size_t)n * 2 + 1];
  float xv[8] = {a4.x, a4.y, a4.z, a4.w, b4.x, b4.y, b4.z, b4.w};
  uint4 pk;
  pk.x = bfpack(xv[0], xv[1]); pk.y = bfpack(xv[2], xv[3]);
  pk.z = bfpack(xv[4], xv[5]); pk.w = bfpack(xv[6], xv[7]);
#define DOT2(p, s0, s1)                                               \
  float s0 = 0.f, s1 = 0.f;                                           \
  for (int d = 0; d < 4; d++) { s0 += xv[d] * p[d]; s1 += xv[4 + d] * p[4 + d]; }
  if (rec0) {
    DOT2(ps0, s0, s1)
    ((uint4*)rec0)[(size_t)n * 2] = pk;
    ((float4*)rec0)[(size_t)n * 2 + 1] = make_float4(s0, s1, 0.f, 0.f);
  }
  if (rec1) {
    DOT2(ps1, s0, s1)
    ((uint4*)rec1)[(size_t)n * 2] = pk;
    ((float4*)rec1)[(size_t)n * 2 + 1] = make_float4(s0, s1, 0.f, 0.f);
  }
  if (pd0) { DOT2(pd0, s0, s1) ((float2*)od0)[n] = make_float2(s0, s1); }
  if (pd1) { DOT2(pd1, s0, s1) ((float2*)od1)[n] = make_float2(s0, s1); }
#undef DOT2
}

// -- partition pass 1 (single pass): LDS-staged bucket-partition with global slot reservation --
// PART per type: bucket b occupies [b*CAP, b*CAP + CNT[b]). One atomicAdd per (block,bucket).
__global__ __launch_bounds__(512) void k_bplace(
    const int* __restrict__ e0p, const int* __restrict__ e1p, const int* __restrict__ e2p,
    int E, int NBmax, int nb0, int nb1, int nb2,
    int* __restrict__ CNT, int* __restrict__ PART)
{
  int ty = blockIdx.y;
  const int* src = ty == 0 ? e0p : (ty == 1 ? e1p : e2p);
  const int* dst = src + E;
  int NBt = ty == 0 ? nb0 : (ty == 1 ? nb1 : nb2);
  int* part = PART + (size_t)ty * NBmax * CAP;
  int* cnt_g = CNT + ty * NBCAP;
  __shared__ int hist[NBCAP];
  __shared__ int lscan[NBCAP + 1];
  __shared__ int base[NBCAP];
  __shared__ int stage[BE];
  __shared__ short bkt[BE];
  __shared__ int ws[8];
  int t = threadIdx.x;
  hist[t] = 0;
  __syncthreads();
  int blk = blockIdx.x;
  int e0 = blk * BE, e1 = min(E, e0 + BE);
  int cnt = e1 - e0;
  int qbase = e0 >> 2, nq = cnt >> 2;
  int dreg[16], sreg[16];
  unsigned short lr[16];
#pragma unroll
  for (int i = 0; i < 4; i++) {
    int q = i * 512 + t;
    if (q < nq) {
      int4 dq = ((const int4*)dst)[qbase + q];
      int4 sq = ((const int4*)src)[qbase + q];
      dreg[i * 4 + 0] = dq.x; dreg[i * 4 + 1] = dq.y;
      dreg[i * 4 + 2] = dq.z; dreg[i * 4 + 3] = dq.w;
      sreg[i * 4 + 0] = sq.x; sreg[i * 4 + 1] = sq.y;
      sreg[i * 4 + 2] = sq.z; sreg[i * 4 + 3] = sq.w;
#pragma unroll
      for (int k = 0; k < 4; k++)
        lr[i * 4 + k] = (unsigned short)atomicAdd(&hist[dreg[i * 4 + k] >> LOGD], 1);
    } else {
#pragma unroll
      for (int k = 0; k < 4; k++) dreg[i * 4 + k] = -1;
    }
  }
  __syncthreads();
  // exclusive scan of 512 hist bins
  {
    int v = hist[t];
    int lane = t & 63, wv = t >> 6;
    int x = v;
#pragma unroll
    for (int o = 1; o < 64; o <<= 1) { int u = __shfl_up(x, o, 64); if (lane >= o) x += u; }
    if (lane == 63) ws[wv] = x;
    __syncthreads();
    if (t == 0) { int s = 0; for (int k = 0; k < 8; k++) { int tmp = ws[k]; ws[k] = s; s += tmp; } }
    __syncthreads();
    int excl = x - v + ws[wv];
    lscan[t] = excl;
    if (t == NBCAP - 1) lscan[NBCAP] = excl + v;
  }
  if (t < NBt) {
    int h = hist[t];
    int res = h ? atomicAdd(&cnt_g[t], h) : 0;
    base[t] = t * CAP + res;
  }
  __syncthreads();
  // fill bkt table; fuse base -= lscan
  {
    int b = t;
    if (b < NBt) {
      int j0 = lscan[b], j1 = lscan[b + 1];
      base[b] -= j0;
      for (int j = j0; j < j1; j++) bkt[j] = (short)b;
    }
  }
  // stage edges sorted by bucket
#pragma unroll
  for (int i = 0; i < 16; i++) {
    int d = dreg[i];
    if (d >= 0) {
      int bk2 = d >> LOGD;
      stage[lscan[bk2] + lr[i]] = (sreg[i] << LOGD) | (d & (DPB - 1));
    }
  }
  __syncthreads();
  for (int j = t; j < cnt; j += 512)
    part[base[bkt[j]] + j] = stage[j];
}

// ---- partition pass 2: per-bucket counting sort (rank-capture) + 257-entry offset tables ----
__global__ __launch_bounds__(512) void k_sort(
    int* __restrict__ PART, const int* __restrict__ CNT, int NBmax,
    int nb0, int nb1, int nb2,
    int* __restrict__ OFF2)
{
  int ty = blockIdx.y;
  int NBt = ty == 0 ? nb0 : (ty == 1 ? nb1 : nb2);
  int bk = blockIdx.x;
  if (bk >= NBt) return;
  int* part = PART + (size_t)ty * NBmax * CAP;
  int cnt = CNT[ty * NBCAP + bk];
  int s0 = bk * CAP, s1 = s0 + cnt;
  __shared__ int hist[DPB];
  __shared__ int binoff[DPB];
  __shared__ int sorted[CAP];
  __shared__ int ws[4];
  int t = threadIdx.x;
  if (t < DPB) hist[t] = 0;
  __syncthreads();
  int myv[24];
  unsigned short myr[24];
#pragma unroll
  for (int it = 0; it < 24; it++) {
    int j = s0 + it * 512 + t;
    if (j < s1) {
      int v = part[j];
      myv[it] = v;
      myr[it] = (unsigned short)atomicAdd(&hist[v & (DPB - 1)], 1);
    } else myv[it] = -1;
  }
  __syncthreads();
  {
    int v = (t < DPB) ? hist[t] : 0;
    int lane = t & 63, wv = t >> 6;
    int x = v;
#pragma unroll
    for (int o = 1; o < 64; o <<= 1) { int u = __shfl_up(x, o, 64); if (lane >= o) x += u; }
    if (t < DPB && lane == 63) ws[wv] = x;
    __syncthreads();
    if (t == 0) { int s = 0; for (int k = 0; k < 4; k++) { int tmp = ws[k]; ws[k] = s; s += tmp; } }
    __syncthreads();
    if (t < DPB) binoff[t] = x - v + ws[wv];
  }
  __syncthreads();
  // per-bucket offset table: 256 starts + 1 end
  int* off2 = OFF2 + ((size_t)ty * NBmax + bk) * (DPB + 1);
  if (t < DPB) off2[t] = s0 + binoff[t];
  if (t == DPB) off2[DPB] = s1;
#pragma unroll
  for (int it = 0; it < 24; it++) {
    int v = myv[it];
    if (v >= 0) sorted[binoff[v & (DPB - 1)] + myr[it]] = v >> LOGD;
  }
  __syncthreads();
  for (int j = t; j < cnt; j += 512) part[s0 + j] = sorted[j];
}

// -- layer-1 gather: 16 lanes/dst, bf16 records, type->XCD swizzle, reg accumulate --
__global__ __launch_bounds__(512) void k_gather1(
    const int* __restrict__ PART, const int* __restrict__ OFF2, int NBmax, int gG,
    const float* __restrict__ r0, const float* __restrict__ ad0, float* __restrict__ o0, int n0,
    const float* __restrict__ r1, const float* __restrict__ ad1, float* __restrict__ o1, int n1,
    const float* __restrict__ r2, const float* __restrict__ ad2, float* __restrict__ o2, int n2)
{
  int bid = blockIdx.x;
  int rr = bid & 7, m = bid >> 3;
  int ty, xb;
  if (rr < 3)      { ty = 0; xb = m * 3 + rr; }
  else if (rr < 6) { ty = 1; xb = m * 3 + (rr - 3); }
  else             { ty = 2; xb = m * 2 + (rr - 6); }
  if (xb >= gG) return;
  const float* rec = ty == 0 ? r0 : (ty == 1 ? r1 : r2);
  const float* ad_ = ty == 0 ? ad0 : (ty == 1 ? ad1 : ad2);
  float* out = ty == 0 ? o0 : (ty == 1 ? o1 : o2);
  int Nt = ty == 0 ? n0 : (ty == 1 ? n1 : n2);
  int g = xb * 512 + threadIdx.x;
  int d = g >> 4, l = g & 15;                // 16 lanes per dst
  if (d >= Nt) return;
  int bk = d >> LOGD, dl = d & (DPB - 1);
  const int* off2 = OFF2 + ((size_t)ty * NBmax + bk) * (DPB + 1);
  const int* part = PART + (size_t)ty * NBmax * CAP;
  int i0 = off2[dl], i1 = off2[dl + 1];
  float2 adv = ((const float2*)ad_)[d];
  float s0 = 0.f, s1 = 0.f;
  float acc[8] = {0.f, 0.f, 0.f, 0.f, 0.f, 0.f, 0.f, 0.f};
  for (int i = i0 + l; i < i1; i += 16) {
    int s = part[i];
    uint4 q = ((const uint4*)rec)[(size_t)s * 2];
    float4 ax = ((const float4*)rec)[(size_t)s * 2 + 1];
    float a0 = ax.x + adv.x; a0 = a0 > 0.f ? a0 : 0.2f * a0;
    float a1 = ax.y + adv.y; a1 = a1 > 0.f ? a1 : 0.2f * a1;
    float e0 = __expf(a0), e1 = __expf(a1);
    s0 += e0; s1 += e1;
    acc[0] += e0 * bflo(q.x); acc[1] += e0 * bfhi(q.x);
    acc[2] += e0 * bflo(q.y); acc[3] += e0 * bfhi(q.y);
    acc[4] += e1 * bflo(q.z); acc[5] += e1 * bfhi(q.z);
    acc[6] += e1 * bflo(q.w); acc[7] += e1 * bfhi(q.w);
  }
#pragma unroll
  for (int mm = 1; mm < 16; mm <<= 1) {
    s0 += __shfl_xor(s0, mm, 16);
    s1 += __shfl_xor(s1, mm, 16);
#pragma unroll
    for (int k = 0; k < 8; k++) acc[k] += __shfl_xor(acc[k], mm, 16);
  }
  if (l) return;
  float r0i = 1.f / (s0 + 1e-16f), r1i = 1.f / (s1 + 1e-16f);
  float4 q0 = make_float4(fmaxf(acc[0] * r0i, 0.f), fmaxf(acc[1] * r0i, 0.f),
                          fmaxf(acc[2] * r0i, 0.f), fmaxf(acc[3] * r0i, 0.f));
  float4 q1 = make_float4(fmaxf(acc[4] * r1i, 0.f), fmaxf(acc[5] * r1i, 0.f),
                          fmaxf(acc[6] * r1i, 0.f), fmaxf(acc[7] * r1i, 0.f));
  ((float4*)out)[(size_t)d * 2] = q0;
  ((float4*)out)[(size_t)d * 2 + 1] = q1;
}

// ------- layer-2 gather: 16 lanes/dst, 16B bf16 records, reg accumulate -------
__global__ __launch_bounds__(512) void k_gather2(
    const int* __restrict__ PART, const int* __restrict__ OFF2, int NBmax,
    int ti0, int ti1,
    const float* __restrict__ r0, const float* __restrict__ ad0, float* __restrict__ o0,
    const float* __restrict__ r1, const float* __restrict__ ad1, float* __restrict__ o1, int N)
{
  int zz = blockIdx.y;
  int ty = zz == 0 ? ti0 : ti1;
  const float* rec = zz == 0 ? r0 : r1;
  const float* ad_ = zz == 0 ? ad0 : ad1;
  float* out = zz == 0 ? o0 : o1;
  int g = blockIdx.x * 512 + threadIdx.x;
  int d = g >> 4, l = g & 15;
  if (d >= N) return;
  int bk = d >> LOGD, dl = d & (DPB - 1);
  const int* off2 = OFF2 + ((size_t)ty * NBmax + bk) * (DPB + 1);
  const int* part = PART + (size_t)ty * NBmax * CAP;
  int i0 = off2[dl], i1 = off2[dl + 1];
  float adv = ad_[d];
  float ssum = 0.f;
  float acc[7] = {0.f, 0.f, 0.f, 0.f, 0.f, 0.f, 0.f};
  for (int i = i0 + l; i < i1; i += 16) {
    int s = part[i];
    uint4 q = ((const uint4*)rec)[s];
    float a = bfhi(q.w) + adv; a = a > 0.f ? a : 0.2f * a;
    float ex = __expf(a);
    ssum += ex;
    acc[0] += ex * bflo(q.x); acc[1] += ex * bfhi(q.x);
    acc[2] += ex * bflo(q.y); acc[3] += ex * bfhi(q.y);
    acc[4] += ex * bflo(q.z); acc[5] += ex * bfhi(q.z);
    acc[6] += ex * bflo(q.w);
  }
#pragma unroll
  for (int mm = 1; mm < 16; mm <<= 1) {
    ssum += __shfl_xor(ssum, mm, 16);
#pragma unroll
    for (int k = 0; k < 7; k++) acc[k] += __shfl_xor(acc[k], mm, 16);
  }
  if (l) return;
  float r = 1.f / (ssum + 1e-16f);
  float4 q0 = make_float4(fmaxf(acc[0] * r, 0.f), fmaxf(acc[1] * r, 0.f),
                          fmaxf(acc[2] * r, 0.f), fmaxf(acc[3] * r, 0.f));
  float4 q1 = make_float4(fmaxf(acc[4] * r, 0.f), fmaxf(acc[5] * r, 0.f),
                          fmaxf(acc[6] * r, 0.f), 0.f);
  ((float4*)out)[(size_t)d * 2] = q0;
  ((float4*)out)[(size_t)d * 2 + 1] = q1;
}

// ---------------- semantic-attention reduction (batched over 2 inputs) ----------------
__global__ __launch_bounds__(256) void k_red(
    const float* __restrict__ hA, const float* __restrict__ hB, int N, int F,
    const float* __restrict__ kw, const float* __restrict__ kb,
    float* __restrict__ redA, float* __restrict__ redB)
{
  const float* h = blockIdx.y ? hB : hA;
  float* red = blockIdx.y ? redB : redA;
  __shared__ float kws[64], kbs[8];
  __shared__ float sm[256 * 8];
  int t = threadIdx.x;
  if (t < F * F) kws[t] = kw[t];
  if (t < F) kbs[t] = kb[t];
  __syncthreads();
  float acc[8] = {0, 0, 0, 0, 0, 0, 0, 0};
  for (int n = blockIdx.x * 256 + t; n < N; n += gridDim.x * 256) {
    const float* row = h + (size_t)n * 8;
    float xv[8];
    for (int k = 0; k < F; k++) xv[k] = row[k];
    for (int f = 0; f < F; f++) {
      float s = kbs[f];
      for (int k = 0; k < F; k++) s += xv[k] * kws[k * F + f];
      acc[f] += tanhf(s);
    }
  }
  for (int f = 0; f < 8; f++) sm[t * 8 + f] = (f < F) ? acc[f] : 0.f;
  __syncthreads();
  for (int s2 = 128; s2 > 0; s2 >>= 1) {
    if (t < s2)
      for (int f = 0; f < 8; f++) sm[t * 8 + f] += sm[(t + s2) * 8 + f];
    __syncthreads();
  }
  if (t < F) atomicAdd(&red[t], sm[t]);
}

// ---------------- semantic attention weights (tiny) ----------------
__global__ void k_attn(const float* __restrict__ red, const float* __restrict__ q,
                       int T, int F, float invN, float* __restrict__ attn)
{
  if (threadIdx.x != 0 || blockIdx.x != 0) return;
  float v[4]; float m = -1e30f;
  for (int t2 = 0; t2 < T; t2++) {
    float s = 0.f;
    for (int f = 0; f < F; f++) s += q[f] * red[t2 * F + f];
    s *= invN;
    v[t2] = s; m = fmaxf(m, s);
  }
  float sum = 0.f;
  for (int t2 = 0; t2 < T; t2++) { v[t2] = __expf(v[t2] - m); sum += v[t2]; }
  for (int t2 = 0; t2 < T; t2++) attn[t2] = v[t2] / sum;
}

// -- layer-2 projection: fused semantic combine (+relu) + packed 16B bf16 record + dst alphas --
__global__ __launch_bounds__(256) void k_proj2(
    const float* __restrict__ h0, const float* __restrict__ h1,
    const float* __restrict__ attn, int N,
    const float* __restrict__ w, const float* __restrict__ b,
    float* __restrict__ rec2, const float* __restrict__ psrc,
    const float* __restrict__ pd0, float* __restrict__ od0,
    const float* __restrict__ pd1, float* __restrict__ od1)
{
  int n = blockIdx.x * blockDim.x + threadIdx.x;
  if (n >= N) return;
  float a0 = 1.f, a1 = 0.f;
  if (attn) { a0 = attn[0]; a1 = attn[1]; }
  float4 u0 = ((const float4*)h0)[(size_t)n * 2];
  float4 u1 = ((const float4*)h0)[(size_t)n * 2 + 1];
  float xv[8] = {u0.x, u0.y, u0.z, u0.w, u1.x, u1.y, u1.z, u1.w};
  if (h1) {
    float4 v0 = ((const float4*)h1)[(size_t)n * 2];
    float4 v1 = ((const float4*)h1)[(size_t)n * 2 + 1];
    float yv[8] = {v0.x, v0.y, v0.z, v0.w, v1.x, v1.y, v1.z, v1.w};
    for (int j = 0; j < 8; j++) xv[j] = a0 * xv[j] + a1 * yv[j];
  }
  for (int j = 0; j < 8; j++) xv[j] = fmaxf(xv[j], 0.f);
  float y[7];
  for (int j = 0; j < 7; j++) y[j] = b[j];
  for (int k = 0; k < 8; k++) {
    float xk = xv[k];
    for (int j = 0; j < 7; j++) y[j] += xk * w[k * 7 + j];
  }
  float ssrc = 0.f;
  for (int j = 0; j < 7; j++) ssrc += y[j] * psrc[j];
  uint4 pk;
  pk.x = bfpack(y[0], y[1]); pk.y = bfpack(y[2], y[3]);
  pk.z = bfpack(y[4], y[5]); pk.w = bfpack(y[6], ssrc);
  ((uint4*)rec2)[n] = pk;
#define DOD(p, o)                                       \
  if (p) {                                              \
    float s = 0.f;                                      \
    for (int j = 0; j < 7; j++) s += y[j] * p[j];       \
    o[n] = s;                                           \
  }
  DOD(pd0, od0) DOD(pd1, od1)
#undef DOD
}

// ---------------- final combine + log_softmax ----------------
__global__ __launch_bounds__(256) void k_final(
    const float* __restrict__ h0, const float* __restrict__ h1,
    const float* __restrict__ attn, float* __restrict__ out, int N)
{
  int n = blockIdx.x * blockDim.x + threadIdx.x;
  if (n >= N) return;
  float a0 = attn[0], a1 = attn[1];
  const float* r0 = h0 + (size_t)n * 8;
  const float* r1 = h1 + (size_t)n * 8;
  float v[7]; float m = -1e30f;
  for (int c = 0; c < 7; c++) { float t = a0 * r0[c] + a1 * r1[c]; v[c] = t; m = fmaxf(m, t); }
  float sum = 0.f;
  for (int c = 0; c < 7; c++) sum += __expf(v[c] - m);
  float lse = m + logf(sum);
  for (int c = 0; c < 7; c++) out[(size_t)n * 7 + c] = v[c] - lse;
}

extern "C" void kernel_launch(void* const* d_in, const int* in_sizes, int n_in,
                              void* d_out, int out_size, void* d_ws, size_t ws_size,
                              hipStream_t stream)
{
  const float* x_p  = (const float*)d_in[0];
  const float* x_a  = (const float*)d_in[1];
  const int*   eipp = (const int*)d_in[2];
  const int*   eipa = (const int*)d_in[3];
  const int*   eiap = (const int*)d_in[4];
  const float* w1p  = (const float*)d_in[5];
  const float* b1p  = (const float*)d_in[6];
  const float* w1a  = (const float*)d_in[7];
  const float* b1a  = (const float*)d_in[8];
  const float* as1pp = (const float*)d_in[9];
  const float* ad1pp = (const float*)d_in[10];
  const float* as1pa = (const float*)d_in[11];
  const float* ad1pa = (const float*)d_in[12];
  const float* as1ap = (const float*)d_in[13];
  const float* ad1ap = (const float*)d_in[14];
  const float* kw1 = (const float*)d_in[15];
  const float* kb1 = (const float*)d_in[16];
  const float* q1  = (const float*)d_in[17];
  const float* w2p = (const float*)d_in[18];
  const float* b2p = (const float*)d_in[19];
  const float* w2a = (const float*)d_in[20];
  const float* b2a = (const float*)d_in[21];
  const float* as2pp = (const float*)d_in[22];
  const float* ad2pp = (const float*)d_in[23];
  // d_in[24]=as2pa, d_in[25]=ad2pa unused: pa edges only feed author nodes,
  // and author layer-2 output is dead (final output is papers only).
  const float* as2ap = (const float*)d_in[26];
  const float* ad2ap = (const float*)d_in[27];
  const float* kw2 = (const float*)d_in[28];
  const float* kb2 = (const float*)d_in[29];
  const float* q2  = (const float*)d_in[30];

  const int NP = in_sizes[0] / DIN;
  const int NA = in_sizes[1] / DIN;
  const int E  = in_sizes[2] / 2;
  (void)n_in; (void)out_size; (void)ws_size;

  const int nblocks = (E + BE - 1) / BE;
  const int NBp = (NP + DPB - 1) >> LOGD;
  const int NBa = (NA + DPB - 1) >> LOGD;
  const int NBmax = NBp > NBa ? NBp : NBa;
  const int nmx  = NP > NA ? NP : NA;

  float* w = (float*)d_ws;
  size_t off_ = 0;
  auto A = [&](size_t n) { float* p = w + off_; off_ += (n + 15) & ~(size_t)15; return p; };
  float* XP_P1 = A((size_t)NP * 8);
  float* XP_A1 = A((size_t)NA * 8);
  float* RECPP = A((size_t)NP * 8);   // 32B bf16 records; reused as REC2P (16B, stride 4)
  float* RECPA = A((size_t)NP * 8);
  float* RECAP = A((size_t)NA * 8);   // reused as REC2A
  float* AD_PP = A((size_t)NP * 2);
  float* AD_PA = A((size_t)NA * 2);
  float* AD_AP = A((size_t)NP * 2);
  float* A2DPP = A((size_t)NP);
  float* A2DAP = A((size_t)NP);
  float* O_PP  = A((size_t)NP * 8);   // reused as O2PP
  float* O_PA  = A((size_t)NA * 8);
  float* O_AP  = A((size_t)NP * 8);   // reused as O2AP
  float* ATT1  = A(2);
  float* ATT2  = A(2);
  // ---- zero-initialized region: RED1, RED2, CNT (contiguous) ----
  float* RED1  = A(16);
  float* RED2  = A(16);
  int*   CNT   = (int*)A(3 * NBCAP);
  int* PART   = (int*)A((size_t)3 * NBmax * CAP);          // padded per-bucket regions
  int* OFF2   = (int*)A((size_t)3 * NBmax * (DPB + 1));    // per-bucket CSR offsets + end

  float* REC2P = RECPP;
  float* REC2A = RECAP;
  float* O2PP  = O_PP;
  float* O2AP  = O_AP;

  hipMemsetAsync(RED1, 0, (32 + 3 * NBCAP) * sizeof(int), stream);  // RED1+RED2+CNT

  dim3 B(256);
  int nbP = (NP + 255) / 256, nbA = (NA + 255) / 256;
  int gG = (nmx * 16 + 511) / 512;                       // gather1 blocks per type (16 lanes/dst)
  int g1blocks = 8 * ((gG + 1) / 2);                     // type->XCD swizzled 1-D grid

  // layer 1 projections + packed bf16 source records + dst alphas
  k_proj1<<<(NP + 31) / 32, B, 0, stream>>>(x_p, w1p, b1p, XP_P1, NP);
  k_proj1<<<(NA + 31) / 32, B, 0, stream>>>(x_a, w1a, b1a, XP_A1, NA);
  k_pack1<<<nbP, B, 0, stream>>>(XP_P1, NP,
      as1pp, RECPP, as1pa, RECPA, ad1pp, AD_PP, ad1ap, AD_AP);
  k_pack1<<<nbA, B, 0, stream>>>(XP_A1, NA,
      as1ap, RECAP, nullptr, nullptr, ad1pa, AD_PA, nullptr, nullptr);

  // single-pass bucket partition (global slot reservation) + per-bucket dst sort
  k_bplace<<<dim3(nblocks, 3), dim3(512), 0, stream>>>(
      eipp, eipa, eiap, E, NBmax, NBp, NBa, NBp, CNT, PART);
  k_sort<<<dim3(NBmax, 3), dim3(512), 0, stream>>>(
      PART, CNT, NBmax, NBp, NBa, NBp, OFF2);

  // layer-1 CSR gathers (bf16 records, type->XCD swizzle, 16 lanes/dst, no atomics)
  k_gather1<<<dim3(g1blocks), dim3(512), 0, stream>>>(
      PART, OFF2, NBmax, gG,
      RECPP, AD_PP, O_PP, NP,
      RECPA, AD_PA, O_PA, NA,
      RECAP, AD_AP, O_AP, NP);

  // layer 1 semantic attention (paper: T=2; author: T=1 -> O_PA passes through)
  k_red<<<dim3(256, 2), B, 0, stream>>>(O_PP, O_AP, NP, 8, kw1, kb1, RED1, RED1 + 8);
  k_attn<<<1, 1, 0, stream>>>(RED1, q1, 2, 8, 1.0f / NP, ATT1);

  // layer 2 projections (paper: fused semantic combine; author: passthrough) + packed records
  k_proj2<<<nbP, B, 0, stream>>>(O_PP, O_AP, ATT1, NP, w2p, b2p,
      REC2P, as2pp, ad2pp, A2DPP, ad2ap, A2DAP);
  k_proj2<<<nbA, B, 0, stream>>>(O_PA, nullptr, nullptr, NA, w2a, b2a,
      REC2A, as2ap, nullptr, nullptr, nullptr, nullptr);

  // layer-2 CSR gathers (pp and ap; author layer-2 output is dead)
  k_gather2<<<dim3((NP * 16 + 511) / 512, 2), dim3(512), 0, stream>>>(
      PART, OFF2, NBmax, 0, 2,
      REC2P, A2DPP, O2PP,
      REC2A, A2DAP, O2AP, NP);

  // layer 2 semantic attention + final log_softmax
  k_red<<<dim3(256, 2), B, 0, stream>>>(O2PP, O2AP, NP, 7, kw2, kb2, RED2, RED2 + 7);
  k_attn<<<1, 1, 0, stream>>>(RED2, q2, 2, 7, 1.0f / NP, ATT2);
  k_final<<<nbP, B, 0, stream>>>(O2PP, O2AP, ATT2, (float*)d_out, NP);
}